// Round 17
// baseline (399.517 us; speedup 1.0000x reference)
//
#include <hip/hip_runtime.h>

#define NG 8000
#define NHALF 4000
#define NG3 24000
#define TS 1440
#define NOUT 32
#define LENFT 72
#define DTC (1.0f/24.0f)
#define NEARZEROC 1e-5f

// gfx950 hardware transcendentals (base-2). Pure ops -> non-volatile asm (CSE ok).
__device__ __forceinline__ float fexp2(float x) {
  float r; asm("v_exp_f32 %0, %1" : "=v"(r) : "v"(x)); return r;
}
__device__ __forceinline__ float flog2(float x) {
  float r; asm("v_log_f32 %0, %1" : "=v"(r) : "v"(x)); return r;
}

typedef const void __attribute__((address_space(1))) gas_void;
typedef void __attribute__((address_space(3)))       las_void;
typedef float v2f __attribute__((ext_vector_type(2)));

// ---------------------------------------------------------------------------
// Kernel 1: per-cell constants + normalized routing weights
// ---------------------------------------------------------------------------
__global__ __launch_bounds__(256) void precompute_kernel(
    const float* __restrict__ p1, const float* __restrict__ p2,
    const float* __restrict__ ac_all,
    float* __restrict__ Cst,   // 16 * NG floats (SoA)
    float* __restrict__ W)     // LENFT * NG floats (k-major)
{
  int n = blockIdx.x * 256 + threadIdx.x;
  if (n >= NG) return;
  const float* r = p1 + n * 19;
  float BETA   = 1.0f   + r[0]  * 5.0f;
  float FC     = 50.0f  + r[1]  * 950.0f;
  float K0     = 0.05f  + r[2]  * 0.85f;
  float K1     = 0.01f  + r[3]  * 0.49f;
  float K2     = 0.001f + r[4]  * 0.199f;
  float LP     = 0.2f   + r[5]  * 0.8f;
  float PERC   =          r[6]  * 10.0f;
  float UZL    =          r[7]  * 100.0f;
  float TT     = -2.5f  + r[8]  * 5.0f;
  float CFMAX  = 0.5f   + r[9]  * 9.5f;
  float CFR    =          r[10] * 0.1f;
  float CWH    =          r[11] * 0.2f;
  float BETAET = 0.3f   + r[12] * 4.7f;
  float Cpar   =          r[13];
  float RT     =          r[14] * 20.0f;
  float AC     =          r[15] * 2500.0f;
  float F0     = 120.0f + r[16] * 2760.0f;
  float FMIN   =          r[17];
  float ALPHA  = 0.5f   + r[18] * 4.5f;

  float ac  = ac_all[n];
  float fmx = DTC * F0 * (FMIN + (1.0f - FMIN) * expf(-powf(ac / (AC + 1.0f), 1.0f / ALPHA)));

  Cst[ 0*NG+n] = TT;            Cst[ 1*NG+n] = CFMAX * DTC;
  Cst[ 2*NG+n] = CFR*CFMAX*DTC; Cst[ 3*NG+n] = CWH;
  Cst[ 4*NG+n] = fmx;           Cst[ 5*NG+n] = 1.0f / FC;
  Cst[ 6*NG+n] = BETA;          Cst[ 7*NG+n] = FC;
  Cst[ 8*NG+n] = Cpar;          Cst[ 9*NG+n] = 1.0f / (LP * FC);
  Cst[10*NG+n] = BETAET;        Cst[11*NG+n] = PERC * DTC;
  Cst[12*NG+n] = K0 * DTC;      Cst[13*NG+n] = UZL;
  Cst[14*NG+n] = K1 * DTC;      Cst[15*NG+n] = K2 * DTC;

  // routing weights (gamma kernel), normalized
  float a   = fmaxf(p2[n*3+0] * 5.0f,  0.01f);
  float b   = fmaxf(p2[n*3+1] * 12.0f, 0.01f);
  float lag = p2[n*3+2] * 48.0f + RT;
  float am1 = a - 1.0f, invb = 1.0f / b;
  float sum = 0.0f;
  for (int k = 0; k < LENFT; k++) {
    float s  = (k + 0.5f) - lag;
    float sm = fmaxf(s, 1e-6f);
    float wv = (s > 0.0f) ? expf(am1 * logf(sm) - sm * invb) : 0.0f;
    sum += wv;
  }
  float inv = 1.0f / (sum + 1e-8f);
  for (int k = 0; k < LENFT; k++) {
    float s  = (k + 0.5f) - lag;
    float sm = fmaxf(s, 1e-6f);
    float wv = (s > 0.0f) ? expf(am1 * logf(sm) - sm * invb) : 0.0f;
    W[k*NG + n] = wv * inv;
  }
}

// ---------------------------------------------------------------------------
// Kernel 2: sequential HBV scan — PACKED FP32 (v_pk_*) over cell pairs.
// r13's interleave failed because source order is only a scheduling hint the
// compiler may re-serialize; ext_vector float2 ops lower to <2 x float> IR ->
// v_pk_fma/add/mul/min/max, baking the 2-cell interleave into the ISA.
// Pair = cells (2i, 2i+1): adjacent in x (one 24B strip/step) and in Q
// (one 8B store/step). Unpackable (4 transcendentals, cndmask, med3) stays
// element-wise. 63 blocks x 64 thr = 63 CUs; BW ~0.7 TB/s << 63-CU ceiling.
// ---------------------------------------------------------------------------
struct HbvConst2 {
  v2f TT, CFMAXDT, CFRDT, CWH, FMX, IFC, BETA, FC, C, ILF, BETAET,
      PERCDT, K0DT, UZL, K1DT, K2DT;
};

__device__ __forceinline__ v2f ldc2(const float* __restrict__ Cst, int j, int i2) {
  return *reinterpret_cast<const v2f*>(Cst + j * NG + i2);
}

__device__ __forceinline__ v2f hbv_step2p(v2f P, v2f Tm, v2f PET,
    const HbvConst2& c, v2f& SP, v2f& MW, v2f& SM, v2f& SUZ, v2f& SLZ)
{
  const v2f vzero = 0.0f, vone = 1.0f, veps = NEARZEROC;
  v2f rain, k;
  rain.x = (Tm.x >= c.TT.x) ? P.x : 0.0f;
  rain.y = (Tm.y >= c.TT.y) ? P.y : 0.0f;
  k.x    = (Tm.x >= c.TT.x) ? c.CFMAXDT.x : c.CFRDT.x;
  k.y    = (Tm.y >= c.TT.y) ? c.CFMAXDT.y : c.CFRDT.y;
  v2f dT = Tm - c.TT;
  SP += P - rain;
  v2f kd = k * dT;
  v2f tr;  // fused melt/refr (exact; see r14 proof)
  tr.x = __builtin_amdgcn_fmed3f(kd.x, -MW.x, SP.x);
  tr.y = __builtin_amdgcn_fmed3f(kd.y, -MW.y, SP.y);
  MW += tr; SP -= tr;
  v2f tosoil = __builtin_elementwise_max(MW - c.CWH * SP, vzero);
  MW -= tosoil;
  v2f win   = rain + tosoil;
  v2f infil = __builtin_elementwise_min(win, c.FMX);
  v2f qie   = win - infil;
  v2f lg, sw;
  lg.x = flog2(SM.x * c.IFC.x);  lg.y = flog2(SM.y * c.IFC.y);
  sw.x = fexp2(c.BETA.x * lg.x); sw.y = fexp2(c.BETA.y * lg.y);
  sw = __builtin_elementwise_min(sw, vone);
  v2f rech = infil * sw;
  SM += infil - rech;
  v2f excess = __builtin_elementwise_max(SM - c.FC, vzero);
  SM -= excess;
  v2f u   = __builtin_elementwise_max(vone - SM * c.IFC, vzero);  // cap min dead: C*u<=1
  v2f cap = c.C * SLZ * u;
  SM += cap; SLZ -= cap;
  v2f lg2, ef;
  lg2.x = flog2(SM.x * c.ILF.x);    lg2.y = flog2(SM.y * c.ILF.y);
  ef.x  = fexp2(c.BETAET.x * lg2.x); ef.y = fexp2(c.BETAET.y * lg2.y);
  ef = __builtin_elementwise_min(ef, vone);
  SM = __builtin_elementwise_max(SM - PET * ef, veps);   // et min folded (exact)
  SUZ += rech + excess;
  v2f perc = __builtin_elementwise_min(SUZ, c.PERCDT);
  SUZ -= perc;
  v2f q0 = c.K0DT * __builtin_elementwise_max(SUZ - c.UZL, vzero);
  SUZ -= q0;
  v2f q1 = c.K1DT * SUZ;
  SUZ -= q1;
  SLZ += perc;
  v2f q2 = c.K2DT * SLZ;
  SLZ -= q2;
  return qie + q0 + q1 + q2;
}

// stage 8 steps of the pair's (P0,T0,E0,P1,T1,E1) strip as 3 v2f loads/step
#define LOADP8(A, T0)                                                         \
  { _Pragma("unroll")                                                         \
    for (int k_ = 0; k_ < 8; k_++) {                                          \
      const float* b_ = xp + (size_t)((T0) + k_) * NG3;                       \
      A[k_][0] = *reinterpret_cast<const v2f*>(b_);                           \
      A[k_][1] = *reinterpret_cast<const v2f*>(b_ + 2);                       \
      A[k_][2] = *reinterpret_cast<const v2f*>(b_ + 4);                       \
    } }

// unpack strip regs -> (P,T,E) pairs and run one step, storing one dwordx2
#define STEPP(A, k_, t_)                                                      \
  { v2f P_  = {A[k_][0].x, A[k_][1].y};                                       \
    v2f Tm_ = {A[k_][0].y, A[k_][2].x};                                       \
    v2f E_  = {A[k_][1].x, A[k_][2].y};                                       \
    v2f q_  = hbv_step2p(P_, Tm_, E_, c, SP, MW, SM, SUZ, SLZ);               \
    *reinterpret_cast<v2f*>(Q + (size_t)(t_) * NG + i2) = q_; }

__global__ __launch_bounds__(64, 1) void scan_kernel(
    const float* __restrict__ x, const float* __restrict__ Cst,
    float* __restrict__ Q)
{
  int i = blockIdx.x * 64 + threadIdx.x;     // pair index
  if (i >= NHALF) return;
  int i2 = 2 * i;

  HbvConst2 c;
  c.TT    =ldc2(Cst, 0,i2); c.CFMAXDT=ldc2(Cst, 1,i2); c.CFRDT =ldc2(Cst, 2,i2);
  c.CWH   =ldc2(Cst, 3,i2); c.FMX    =ldc2(Cst, 4,i2); c.IFC   =ldc2(Cst, 5,i2);
  c.BETA  =ldc2(Cst, 6,i2); c.FC     =ldc2(Cst, 7,i2); c.C     =ldc2(Cst, 8,i2);
  c.ILF   =ldc2(Cst, 9,i2); c.BETAET =ldc2(Cst,10,i2); c.PERCDT=ldc2(Cst,11,i2);
  c.K0DT  =ldc2(Cst,12,i2); c.UZL    =ldc2(Cst,13,i2); c.K1DT  =ldc2(Cst,14,i2);
  c.K2DT  =ldc2(Cst,15,i2);

  v2f SP = 1e-3f, MW = 1e-3f, SM = 1e-3f, SUZ = 1e-3f, SLZ = 1e-3f;
  const float* xp = x + (size_t)6 * i;       // pair's 24B strip base

  v2f bufA[8][3], bufB[8][3];
  LOADP8(bufA, 0);
  for (int tb = 0; tb < TS; tb += 16) {
    LOADP8(bufB, tb + 8);                    // prefetch next 8 steps
    #pragma unroll
    for (int kk = 0; kk < 8; kk++) STEPP(bufA, kk, tb + kk);
    if (tb + 16 < TS) LOADP8(bufA, tb + 16);
    #pragma unroll
    for (int kk = 0; kk < 8; kk++) STEPP(bufB, kk, tb + 8 + kk);
  }
}

// ---------------------------------------------------------------------------
// Kernel 3: fused routing FIR (72 taps) + partial einsum — UNCHANGED (r12).
// gll staging, async stage(sub+1) under einsum, bijective XCD chunk swizzle.
// ---------------------------------------------------------------------------
#define TTILE 48
#define NTILES_T 30          // 1440 / 48
#define NSPLIT 25
#define SUBS 5               // subtiles per split (25*5*64 = 8000)
#define QROWS (TTILE + 71)   // 119
#define NWG (NTILES_T * NSPLIT)  // 750

__global__ __launch_bounds__(256, 2) void route_kernel(
    const float* __restrict__ Q, const float* __restrict__ W,
    const float* __restrict__ topo, const float* __restrict__ areas,
    float* __restrict__ Par)   // [NSPLIT][TS][NOUT]
{
  __shared__ float Qs[QROWS][64];   // 30.5 KB
  __shared__ float Ws[LENFT][64];   // 18.4 KB
  __shared__ float Rs[TTILE][68];   // 13.1 KB (pad 68: float4-aligned rows)

  int bid  = blockIdx.x;
  int xcd  = bid & 7, pos = bid >> 3;
  const int q = NWG / 8, r = NWG % 8;              // 93, 6
  int wgid = ((xcd < r) ? xcd * (q + 1) : r * (q + 1) + (xcd - r) * q) + pos;
  int tile  = wgid % NTILES_T;      // consecutive wgid -> consecutive tiles
  int split = wgid / NTILES_T;
  int t0    = tile * TTILE;
  int tid   = threadIdx.x;
  int wid   = tid >> 6, lane = tid & 63;

  int nn = tid & 63;                // conv: cell within subtile
  int tc = wid * 12;                // conv: 12 consecutive t-rows
  int oe = tid & 31;                // einsum: outlet
  int te = (tid >> 5) * 6;          // einsum: 6 consecutive t-rows

  auto stage = [&](int sub) {
    int n0 = (split * SUBS + sub) * 64;
    for (int rr = wid; rr < QROWS; rr += 4) {
      int t = t0 - 71 + rr;
      if (t >= 0)
        __builtin_amdgcn_global_load_lds(
            (gas_void*)(Q + (size_t)t * NG + n0 + lane),
            (las_void*)(&Qs[rr][0]), 4, 0, 0);
      else
        Qs[rr][lane] = 0.0f;
    }
    for (int k = wid; k < LENFT; k += 4)
      __builtin_amdgcn_global_load_lds(
          (gas_void*)(W + (size_t)k * NG + n0 + lane),
          (las_void*)(&Ws[k][0]), 4, 0, 0);
  };

  float acc_out[6] = {0.f, 0.f, 0.f, 0.f, 0.f, 0.f};

  stage(0);
  for (int sub = 0; sub < SUBS; sub++) {
    int n0 = (split * SUBS + sub) * 64;

    float4 Greg[16];
    #pragma unroll
    for (int g4 = 0; g4 < 16; g4++) {
      float4 tv = *reinterpret_cast<const float4*>(&topo[oe * NG + n0 + g4 * 4]);
      float4 av = *reinterpret_cast<const float4*>(&areas[n0 + g4 * 4]);
      Greg[g4] = make_float4(tv.x * av.x, tv.y * av.y, tv.z * av.z, tv.w * av.w);
    }

    __syncthreads();   // staging(sub) complete

    float acc[12];
    float qwin[12];
    #pragma unroll
    for (int i = 0; i < 12; i++) { acc[i] = 0.0f; qwin[i] = Qs[tc + i][nn]; }
    #pragma unroll
    for (int kk = 0; kk < LENFT; kk++) {
      float w = Ws[71 - kk][nn];
      #pragma unroll
      for (int i = 0; i < 12; i++) acc[i] += w * qwin[i];
      #pragma unroll
      for (int i = 0; i < 11; i++) qwin[i] = qwin[i + 1];
      if (kk < 71) qwin[11] = Qs[tc + 12 + kk][nn];
    }
    #pragma unroll
    for (int i = 0; i < 12; i++) Rs[tc + i][nn] = acc[i];
    __syncthreads();   // Rs visible; Qs/Ws reads done

    if (sub + 1 < SUBS) stage(sub + 1);   // overlaps with einsum below

    #pragma unroll
    for (int g4 = 0; g4 < 16; g4++) {
      float4 g = Greg[g4];
      #pragma unroll
      for (int p = 0; p < 6; p++) {
        float4 rv = *reinterpret_cast<const float4*>(&Rs[te + p][g4 * 4]);
        acc_out[p] += rv.x * g.x + rv.y * g.y + rv.z * g.z + rv.w * g.w;
      }
    }
  }

  #pragma unroll
  for (int p = 0; p < 6; p++) {
    int tg = t0 + te + p;           // always < 1440 (30*48 exact)
    Par[(split * TS + tg) * NOUT + oe] = acc_out[p];
  }
}

// ---------------------------------------------------------------------------
// Kernel 4: reduce partials over the 25 n-splits
// ---------------------------------------------------------------------------
__global__ __launch_bounds__(256) void reduce_kernel(
    const float* __restrict__ Par, float* __restrict__ out)
{
  int i = blockIdx.x * 256 + threadIdx.x;
  if (i < TS * NOUT) {
    float s = 0.0f;
    #pragma unroll
    for (int sp = 0; sp < NSPLIT; sp++) s += Par[sp * (TS * NOUT) + i];
    out[i] = s;
  }
}

// ---------------------------------------------------------------------------
extern "C" void kernel_launch(void* const* d_in, const int* in_sizes, int n_in,
                              void* d_out, int out_size, void* d_ws, size_t ws_size,
                              hipStream_t stream)
{
  const float* x_phy  = (const float*)d_in[0];
  const float* ac_all = (const float*)d_in[1];
  // d_in[2] = elev_all (unused by reference)
  const float* topo   = (const float*)d_in[3];
  const float* areas  = (const float*)d_in[4];
  const float* p1     = (const float*)d_in[5];
  const float* p2     = (const float*)d_in[6];
  float* out = (float*)d_out;

  char* ws = (char*)d_ws;
  float* Q   = (float*)(ws);                                  // 46,080,000 B
  float* W   = (float*)(ws + 46080000);                       //  2,304,000 B
  float* Cst = (float*)(ws + 46080000 + 2304000);             //    512,000 B
  float* Par = (float*)(ws + 46080000 + 2304000 + 512000);    //  4,608,000 B

  hipLaunchKernelGGL(precompute_kernel, dim3(32), dim3(256), 0, stream,
                     p1, p2, ac_all, Cst, W);
  hipLaunchKernelGGL(scan_kernel, dim3((NHALF + 63) / 64), dim3(64), 0, stream,
                     x_phy, Cst, Q);
  hipLaunchKernelGGL(route_kernel, dim3(NWG), dim3(256), 0, stream,
                     Q, W, topo, areas, Par);
  hipLaunchKernelGGL(reduce_kernel, dim3((TS * NOUT + 255) / 256), dim3(256), 0, stream,
                     Par, out);
}